// Round 3
// baseline (1056.028 us; speedup 1.0000x reference)
//
#include <hip/hip_runtime.h>
#include <stdint.h>

#define NB 8
#define NT 32
#define NN 1024
#define KSEL 16

typedef unsigned long long u64;
typedef unsigned int u32;

// total output element offsets (all float32)
#define O_IDX0 0ull
#define O_DIST 4194304ull
#define O_IDX1 8388608ull
#define O_PTS  12582912ull
#define O_PF   25165824ull
#define O_NORM 50331648ull
#define O_OUTX 62914560ull

__device__ __forceinline__ u32 fmap(float f) {
    u32 b = __float_as_uint(f);
    u32 m = (u32)((int)b >> 31) | 0x80000000u;
    return b ^ m;
}
__device__ __forceinline__ float funmap(u32 m) {
    u32 mask = (m & 0x80000000u) ? 0x80000000u : 0xFFFFFFFFu;
    return __uint_as_float(m ^ mask);
}
// XLA-CPU reduce(sum(x*x)) with LLVM FMA contraction:
// acc=add(acc,elem) chain -> fma(z,z, fma(x,x, y*y))
__device__ __forceinline__ float sq3(float x, float y, float z) {
    return __fmaf_rn(z, z, __fmaf_rn(x, x, __fmul_rn(y, y)));
}
// Eigen sgemm ascending-k FMA dot; d2 = (q2+p2) - 2*dot (2*dot exact)
__device__ __forceinline__ float d2f(float qx, float qy, float qz, float q2, float4 c) {
    float dot = __fmul_rn(qx, c.x);
    dot = __fmaf_rn(qy, c.y, dot);
    dot = __fmaf_rn(qz, c.z, dot);
    return __fsub_rn(__fadd_rn(q2, c.w), __fadd_rn(dot, dot));
}

// ---------------- Phase 1: nearest-neighbor chain (k=1), writes outx ----------------
// grid: 256 blocks (8 batches x 32), block: 256 threads = 32 queries x 8 lanes
__global__ __launch_bounds__(256) void chain_k(const float* __restrict__ P,
                                               float* __restrict__ outx) {
    __shared__ float4 sF[NN];
    const int tid = threadIdx.x;
    const int b = blockIdx.x >> 5;
    const int q = ((blockIdx.x & 31) << 5) + (tid >> 3);
    const int l = tid & 7;
    const float* bp = P + (size_t)b * NT * NN * 3;

    float cx = bp[q * 3 + 0], cy = bp[q * 3 + 1], cz = bp[q * 3 + 2];

    for (int t = 0; t < NT; ++t) {
        // stage frame t with |p|^2 (thread i -> candidates 4i..4i+3)
        const float4* f4 = (const float4*)(bp + (size_t)t * NN * 3);
        float4 A = f4[tid * 3 + 0], Bv = f4[tid * 3 + 1], C = f4[tid * 3 + 2];
        sF[tid * 4 + 0] = make_float4(A.x, A.y, A.z, sq3(A.x, A.y, A.z));
        sF[tid * 4 + 1] = make_float4(A.w, Bv.x, Bv.y, sq3(A.w, Bv.x, Bv.y));
        sF[tid * 4 + 2] = make_float4(Bv.z, Bv.w, C.x, sq3(Bv.z, Bv.w, C.x));
        sF[tid * 4 + 3] = make_float4(C.y, C.z, C.w, sq3(C.y, C.z, C.w));
        __syncthreads();

        float q2 = sq3(cx, cy, cz);
        u64 best = ~0ull;
        #pragma unroll 8
        for (int jj = 0; jj < NN / 8; ++jj) {
            int j = (jj << 3) | l;  // interleaved -> conflict-free b128 broadcast
            float d2 = d2f(cx, cy, cz, q2, sF[j]);
            u64 key = ((u64)fmap(d2) << 32) | (u32)j;
            if (key < best) best = key;
        }
        // reduce argmin across the 8 lanes of this query's group
        #pragma unroll
        for (int off = 1; off < 8; off <<= 1) {
            u64 o = __shfl_xor(best, off);
            if (o < best) best = o;
        }
        int bi = (int)(u32)best;
        float4 w = sF[bi];
        cx = w.x; cy = w.y; cz = w.z;
        if (l == 0) {
            float* o = outx + ((size_t)(b * NT + t) * NN + q) * 3;
            o[0] = cx; o[1] = cy; o[2] = cz;
        }
        __syncthreads();
    }
}

// ---------------- Phase 2: full top-16 + all outputs, fully parallel over (b,t,q) ----
// grid: 1024 blocks (b:8 x t:32 x qchunk:4), block: 256 threads = 256 queries
__global__ __launch_bounds__(256) void topk_k(const float* __restrict__ P,
                                              const float* __restrict__ outx,
                                              float* __restrict__ out) {
    __shared__ float4 sC[NN];  // frame t   (x,y,z,|p|^2)
    __shared__ float4 sPv[NN]; // frame t-1 (x,y,z,0)
    const int tid = threadIdx.x;
    const int bid = blockIdx.x;
    const int b = bid >> 7;
    const int t = (bid >> 2) & 31;
    const int qc = bid & 3;
    const int q = (qc << 8) | tid;
    const float* bp = P + (size_t)b * NT * NN * 3;

    {
        const float4* f4 = (const float4*)(bp + (size_t)t * NN * 3);
        float4 A = f4[tid * 3 + 0], Bv = f4[tid * 3 + 1], C = f4[tid * 3 + 2];
        sC[tid * 4 + 0] = make_float4(A.x, A.y, A.z, sq3(A.x, A.y, A.z));
        sC[tid * 4 + 1] = make_float4(A.w, Bv.x, Bv.y, sq3(A.w, Bv.x, Bv.y));
        sC[tid * 4 + 2] = make_float4(Bv.z, Bv.w, C.x, sq3(Bv.z, Bv.w, C.x));
        sC[tid * 4 + 3] = make_float4(C.y, C.z, C.w, sq3(C.y, C.z, C.w));
        int tp = (t == 0) ? 0 : (t - 1);
        const float4* g4 = (const float4*)(bp + (size_t)tp * NN * 3);
        A = g4[tid * 3 + 0]; Bv = g4[tid * 3 + 1]; C = g4[tid * 3 + 2];
        sPv[tid * 4 + 0] = make_float4(A.x, A.y, A.z, 0.f);
        sPv[tid * 4 + 1] = make_float4(A.w, Bv.x, Bv.y, 0.f);
        sPv[tid * 4 + 2] = make_float4(Bv.z, Bv.w, C.x, 0.f);
        sPv[tid * 4 + 3] = make_float4(C.y, C.z, C.w, 0.f);
    }
    __syncthreads();

    // query point: x_cur(b,t,q)
    float cx, cy, cz;
    if (t == 0) {
        const float* qp = bp + (size_t)q * 3;
        cx = qp[0]; cy = qp[1]; cz = qp[2];
    } else {
        const float* qp = outx + ((size_t)(b * NT + (t - 1)) * NN + q) * 3;
        cx = qp[0]; cy = qp[1]; cz = qp[2];
    }
    // anchor = pts[b, t=0, q, k=0] = outx[b][0][q]
    const float* ap = outx + ((size_t)(b * NT) * NN + q) * 3;
    float ax = ap[0], ay = ap[1], az = ap[2];

    float q2 = sq3(cx, cy, cz);
    u64 keys[KSEL];
    #pragma unroll
    for (int i = 0; i < KSEL; i++) keys[i] = ~0ull;

    #pragma unroll 4
    for (int j = 0; j < NN; ++j) {
        float d2 = d2f(cx, cy, cz, q2, sC[j]);
        u64 key = ((u64)fmap(d2) << 32) | (u32)j;
        if (key < keys[KSEL - 1]) {
            #pragma unroll
            for (int i = 0; i < KSEL; i++) {
                bool c = key < keys[i];
                u64 lo = c ? key : keys[i];
                u64 hi = c ? keys[i] : key;
                keys[i] = lo;
                key = hi;
            }
        }
    }

    size_t g = (size_t)(b * NT + t) * NN + q;

    // idxs (x2) and dist
    #pragma unroll
    for (int kk = 0; kk < KSEL; kk += 4) {
        float4 fi = make_float4((float)(u32)keys[kk + 0], (float)(u32)keys[kk + 1],
                                (float)(u32)keys[kk + 2], (float)(u32)keys[kk + 3]);
        float4 fd = make_float4(funmap((u32)(keys[kk + 0] >> 32)), funmap((u32)(keys[kk + 1] >> 32)),
                                funmap((u32)(keys[kk + 2] >> 32)), funmap((u32)(keys[kk + 3] >> 32)));
        *(float4*)(out + O_IDX0 + g * 16 + kk) = fi;
        *(float4*)(out + O_IDX1 + g * 16 + kk) = fi;
        *(float4*)(out + O_DIST + g * 16 + kk) = fd;
    }

    // pts, normalized, patchlet_feats
    #pragma unroll
    for (int kk = 0; kk < KSEL; kk += 4) {
        u32 i0 = (u32)keys[kk + 0], i1 = (u32)keys[kk + 1], i2 = (u32)keys[kk + 2], i3 = (u32)keys[kk + 3];
        float4 p0 = sC[i0], p1 = sC[i1], p2v = sC[i2], p3 = sC[i3];
        float4 f0 = sPv[i0], f1 = sPv[i1], f2v = sPv[i2], f3 = sPv[i3];
        float n0x = p0.x - ax, n0y = p0.y - ay, n0z = p0.z - az;
        float n1x = p1.x - ax, n1y = p1.y - ay, n1z = p1.z - az;
        float n2x = p2v.x - ax, n2y = p2v.y - ay, n2z = p2v.z - az;
        float n3x = p3.x - ax, n3y = p3.y - ay, n3z = p3.z - az;

        float* pp = out + O_PTS + g * 48 + kk * 3;
        ((float4*)pp)[0] = make_float4(p0.x, p0.y, p0.z, p1.x);
        ((float4*)pp)[1] = make_float4(p1.y, p1.z, p2v.x, p2v.y);
        ((float4*)pp)[2] = make_float4(p2v.z, p3.x, p3.y, p3.z);

        float* np = out + O_NORM + g * 48 + kk * 3;
        ((float4*)np)[0] = make_float4(n0x, n0y, n0z, n1x);
        ((float4*)np)[1] = make_float4(n1y, n1z, n2x, n2y);
        ((float4*)np)[2] = make_float4(n2z, n3x, n3y, n3z);

        float* fp = out + O_PF + g * 96 + kk * 6;
        ((float4*)fp)[0] = make_float4(f0.x, f0.y, f0.z, n0x);
        ((float4*)fp)[1] = make_float4(n0y, n0z, f1.x, f1.y);
        ((float4*)fp)[2] = make_float4(f1.z, n1x, n1y, n1z);
        ((float4*)fp)[3] = make_float4(f2v.x, f2v.y, f2v.z, n2x);
        ((float4*)fp)[4] = make_float4(n2y, n2z, f3.x, f3.y);
        ((float4*)fp)[5] = make_float4(f3.z, n3x, n3y, n3z);
    }
}

extern "C" void kernel_launch(void* const* d_in, const int* in_sizes, int n_in,
                              void* d_out, int out_size, void* d_ws, size_t ws_size,
                              hipStream_t stream) {
    const float* P = (const float*)d_in[0];
    float* out = (float*)d_out;
    float* outx = out + O_OUTX;
    chain_k<<<dim3(256), dim3(256), 0, stream>>>(P, outx);
    topk_k<<<dim3(1024), dim3(256), 0, stream>>>(P, outx, out);
}

// Round 4
// 926.363 us; speedup vs baseline: 1.1400x; 1.1400x over previous
//
#include <hip/hip_runtime.h>
#include <stdint.h>

#define NB 8
#define NT 32
#define NN 1024
#define KSEL 16

typedef unsigned long long u64;
typedef unsigned int u32;

// total output element offsets (all float32)
#define O_IDX0 0ull
#define O_DIST 4194304ull
#define O_IDX1 8388608ull
#define O_PTS  12582912ull
#define O_PF   25165824ull
#define O_NORM 50331648ull
#define O_OUTX 62914560ull

__device__ __forceinline__ u32 fmap(float f) {
    u32 b = __float_as_uint(f);
    u32 m = (u32)((int)b >> 31) | 0x80000000u;
    return b ^ m;
}
__device__ __forceinline__ float funmap(u32 m) {
    u32 mask = (m & 0x80000000u) ? 0x80000000u : 0xFFFFFFFFu;
    return __uint_as_float(m ^ mask);
}
// XLA-CPU reduce(sum(x*x)) with LLVM FMA contraction:
// acc=add(acc,elem) chain -> fma(z,z, fma(x,x, y*y))
__device__ __forceinline__ float sq3(float x, float y, float z) {
    return __fmaf_rn(z, z, __fmaf_rn(x, x, __fmul_rn(y, y)));
}
// Eigen sgemm ascending-k FMA dot; d2 = (q2+p2) - 2*dot (2*dot exact)
__device__ __forceinline__ float d2f(float qx, float qy, float qz, float q2, float4 c) {
    float dot = __fmul_rn(qx, c.x);
    dot = __fmaf_rn(qy, c.y, dot);
    dot = __fmaf_rn(qz, c.z, dot);
    return __fsub_rn(__fadd_rn(q2, c.w), __fadd_rn(dot, dot));
}

// ---------------- Phase 1: nearest-neighbor chain (k=1), writes outx ----------------
// grid: 256 blocks (8 batches x 32), block: 256 threads = 32 queries x 8 lanes
__global__ __launch_bounds__(256) void chain_k(const float* __restrict__ P,
                                               float* __restrict__ outx) {
    __shared__ float4 sF[NN];
    const int tid = threadIdx.x;
    const int b = blockIdx.x >> 5;
    const int q = ((blockIdx.x & 31) << 5) + (tid >> 3);
    const int l = tid & 7;
    const float* bp = P + (size_t)b * NT * NN * 3;

    float cx = bp[q * 3 + 0], cy = bp[q * 3 + 1], cz = bp[q * 3 + 2];

    for (int t = 0; t < NT; ++t) {
        // stage frame t with |p|^2 (thread i -> candidates 4i..4i+3)
        const float4* f4 = (const float4*)(bp + (size_t)t * NN * 3);
        float4 A = f4[tid * 3 + 0], Bv = f4[tid * 3 + 1], C = f4[tid * 3 + 2];
        sF[tid * 4 + 0] = make_float4(A.x, A.y, A.z, sq3(A.x, A.y, A.z));
        sF[tid * 4 + 1] = make_float4(A.w, Bv.x, Bv.y, sq3(A.w, Bv.x, Bv.y));
        sF[tid * 4 + 2] = make_float4(Bv.z, Bv.w, C.x, sq3(Bv.z, Bv.w, C.x));
        sF[tid * 4 + 3] = make_float4(C.y, C.z, C.w, sq3(C.y, C.z, C.w));
        __syncthreads();

        float q2 = sq3(cx, cy, cz);
        u64 best = ~0ull;
        #pragma unroll 8
        for (int jj = 0; jj < NN / 8; ++jj) {
            int j = (jj << 3) | l;  // interleaved -> conflict-free b128 broadcast
            float d2 = d2f(cx, cy, cz, q2, sF[j]);
            u64 key = ((u64)fmap(d2) << 32) | (u32)j;
            if (key < best) best = key;
        }
        // reduce argmin across the 8 lanes of this query's group
        #pragma unroll
        for (int off = 1; off < 8; off <<= 1) {
            u64 o = __shfl_xor(best, off);
            if (o < best) best = o;
        }
        int bi = (int)(u32)best;
        float4 w = sF[bi];
        cx = w.x; cy = w.y; cz = w.z;
        if (l == 0) {
            float* o = outx + ((size_t)(b * NT + t) * NN + q) * 3;
            o[0] = cx; o[1] = cy; o[2] = cz;
        }
        __syncthreads();
    }
}

// ---------------- Phase 2: full top-16 + all outputs, fully parallel over (b,t,q) ----
// grid: 1024 blocks (b:8 x t:32 x qchunk:4), block: 256 threads = 256 queries
__global__ __launch_bounds__(256) void topk_k(const float* __restrict__ P,
                                              const float* __restrict__ outx,
                                              float* __restrict__ out) {
    __shared__ float4 sC[NN];  // frame t   (x,y,z,|p|^2)
    __shared__ float4 sPv[NN]; // frame t-1 (x,y,z,0)
    const int tid = threadIdx.x;
    const int bid = blockIdx.x;
    const int b = bid >> 7;
    const int t = (bid >> 2) & 31;
    const int qc = bid & 3;
    const int q = (qc << 8) | tid;
    const float* bp = P + (size_t)b * NT * NN * 3;

    {
        const float4* f4 = (const float4*)(bp + (size_t)t * NN * 3);
        float4 A = f4[tid * 3 + 0], Bv = f4[tid * 3 + 1], C = f4[tid * 3 + 2];
        sC[tid * 4 + 0] = make_float4(A.x, A.y, A.z, sq3(A.x, A.y, A.z));
        sC[tid * 4 + 1] = make_float4(A.w, Bv.x, Bv.y, sq3(A.w, Bv.x, Bv.y));
        sC[tid * 4 + 2] = make_float4(Bv.z, Bv.w, C.x, sq3(Bv.z, Bv.w, C.x));
        sC[tid * 4 + 3] = make_float4(C.y, C.z, C.w, sq3(C.y, C.z, C.w));
        int tp = (t == 0) ? 0 : (t - 1);
        const float4* g4 = (const float4*)(bp + (size_t)tp * NN * 3);
        A = g4[tid * 3 + 0]; Bv = g4[tid * 3 + 1]; C = g4[tid * 3 + 2];
        sPv[tid * 4 + 0] = make_float4(A.x, A.y, A.z, 0.f);
        sPv[tid * 4 + 1] = make_float4(A.w, Bv.x, Bv.y, 0.f);
        sPv[tid * 4 + 2] = make_float4(Bv.z, Bv.w, C.x, 0.f);
        sPv[tid * 4 + 3] = make_float4(C.y, C.z, C.w, 0.f);
    }
    __syncthreads();

    // query point: x_cur(b,t,q)
    float cx, cy, cz;
    if (t == 0) {
        const float* qp = bp + (size_t)q * 3;
        cx = qp[0]; cy = qp[1]; cz = qp[2];
    } else {
        const float* qp = outx + ((size_t)(b * NT + (t - 1)) * NN + q) * 3;
        cx = qp[0]; cy = qp[1]; cz = qp[2];
    }
    // anchor = pts[b, t=0, q, k=0] = outx[b][0][q]
    const float* ap = outx + ((size_t)(b * NT) * NN + q) * 3;
    float ax = ap[0], ay = ap[1], az = ap[2];

    float q2 = sq3(cx, cy, cz);
    u64 S[KSEL];
    #pragma unroll
    for (int i = 0; i < KSEL; i++) S[i] = ~0ull;

    // branchless streaming top-16: parallel position-local sorted insert.
    // lt[] is monotone (S sorted ascending), depth-3 dataflow, no exec-mask churn.
    #pragma unroll 4
    for (int j = 0; j < NN; ++j) {
        float d2 = d2f(cx, cy, cz, q2, sC[j]);
        u64 key = ((u64)fmap(d2) << 32) | (u32)j;
        bool lt[KSEL];
        #pragma unroll
        for (int i = 0; i < KSEL; i++) lt[i] = key < S[i];
        #pragma unroll
        for (int i = KSEL - 1; i >= 1; --i)
            S[i] = lt[i] ? (lt[i - 1] ? S[i - 1] : key) : S[i];
        S[0] = lt[0] ? key : S[0];
    }

    size_t g = (size_t)(b * NT + t) * NN + q;

    // idxs (x2) and dist
    #pragma unroll
    for (int kk = 0; kk < KSEL; kk += 4) {
        float4 fi = make_float4((float)(u32)S[kk + 0], (float)(u32)S[kk + 1],
                                (float)(u32)S[kk + 2], (float)(u32)S[kk + 3]);
        float4 fd = make_float4(funmap((u32)(S[kk + 0] >> 32)), funmap((u32)(S[kk + 1] >> 32)),
                                funmap((u32)(S[kk + 2] >> 32)), funmap((u32)(S[kk + 3] >> 32)));
        *(float4*)(out + O_IDX0 + g * 16 + kk) = fi;
        *(float4*)(out + O_IDX1 + g * 16 + kk) = fi;
        *(float4*)(out + O_DIST + g * 16 + kk) = fd;
    }

    // pts, normalized, patchlet_feats
    #pragma unroll
    for (int kk = 0; kk < KSEL; kk += 4) {
        u32 i0 = (u32)S[kk + 0], i1 = (u32)S[kk + 1], i2 = (u32)S[kk + 2], i3 = (u32)S[kk + 3];
        float4 p0 = sC[i0], p1 = sC[i1], p2v = sC[i2], p3 = sC[i3];
        float4 f0 = sPv[i0], f1 = sPv[i1], f2v = sPv[i2], f3 = sPv[i3];
        float n0x = p0.x - ax, n0y = p0.y - ay, n0z = p0.z - az;
        float n1x = p1.x - ax, n1y = p1.y - ay, n1z = p1.z - az;
        float n2x = p2v.x - ax, n2y = p2v.y - ay, n2z = p2v.z - az;
        float n3x = p3.x - ax, n3y = p3.y - ay, n3z = p3.z - az;

        float* pp = out + O_PTS + g * 48 + kk * 3;
        ((float4*)pp)[0] = make_float4(p0.x, p0.y, p0.z, p1.x);
        ((float4*)pp)[1] = make_float4(p1.y, p1.z, p2v.x, p2v.y);
        ((float4*)pp)[2] = make_float4(p2v.z, p3.x, p3.y, p3.z);

        float* np = out + O_NORM + g * 48 + kk * 3;
        ((float4*)np)[0] = make_float4(n0x, n0y, n0z, n1x);
        ((float4*)np)[1] = make_float4(n1y, n1z, n2x, n2y);
        ((float4*)np)[2] = make_float4(n2z, n3x, n3y, n3z);

        float* fp = out + O_PF + g * 96 + kk * 6;
        ((float4*)fp)[0] = make_float4(f0.x, f0.y, f0.z, n0x);
        ((float4*)fp)[1] = make_float4(n0y, n0z, f1.x, f1.y);
        ((float4*)fp)[2] = make_float4(f1.z, n1x, n1y, n1z);
        ((float4*)fp)[3] = make_float4(f2v.x, f2v.y, f2v.z, n2x);
        ((float4*)fp)[4] = make_float4(n2y, n2z, f3.x, f3.y);
        ((float4*)fp)[5] = make_float4(f3.z, n3x, n3y, n3z);
    }
}

extern "C" void kernel_launch(void* const* d_in, const int* in_sizes, int n_in,
                              void* d_out, int out_size, void* d_ws, size_t ws_size,
                              hipStream_t stream) {
    const float* P = (const float*)d_in[0];
    float* out = (float*)d_out;
    float* outx = out + O_OUTX;
    chain_k<<<dim3(256), dim3(256), 0, stream>>>(P, outx);
    topk_k<<<dim3(1024), dim3(256), 0, stream>>>(P, outx, out);
}

// Round 5
// 817.550 us; speedup vs baseline: 1.2917x; 1.1331x over previous
//
#include <hip/hip_runtime.h>
#include <stdint.h>

#define NB 8
#define NT 32
#define NN 1024
#define KSEL 16

typedef unsigned long long u64;
typedef unsigned int u32;

// total output element offsets (all float32)
#define O_IDX0 0ull
#define O_DIST 4194304ull
#define O_IDX1 8388608ull
#define O_PTS  12582912ull
#define O_PF   25165824ull
#define O_NORM 50331648ull
#define O_OUTX 62914560ull

__device__ __forceinline__ u32 fmap(float f) {
    u32 b = __float_as_uint(f);
    u32 m = (u32)((int)b >> 31) | 0x80000000u;
    return b ^ m;
}
// XLA-CPU reduce(sum(x*x)) with LLVM FMA contraction:
// acc=add(acc,elem) chain -> fma(z,z, fma(x,x, y*y))
__device__ __forceinline__ float sq3(float x, float y, float z) {
    return __fmaf_rn(z, z, __fmaf_rn(x, x, __fmul_rn(y, y)));
}
// Eigen sgemm ascending-k FMA dot; d2 = (q2+p2) - 2*dot (2*dot exact)
__device__ __forceinline__ float d2f(float qx, float qy, float qz, float q2, float4 c) {
    float dot = __fmul_rn(qx, c.x);
    dot = __fmaf_rn(qy, c.y, dot);
    dot = __fmaf_rn(qz, c.z, dot);
    return __fsub_rn(__fadd_rn(q2, c.w), __fadd_rn(dot, dot));
}

// ---------------- Phase 1: nearest-neighbor chain (k=1), writes outx ----------------
// grid: 256 blocks (8 batches x 32), block: 256 threads = 32 queries x 8 lanes
__global__ __launch_bounds__(256) void chain_k(const float* __restrict__ P,
                                               float* __restrict__ outx) {
    __shared__ float4 sF[NN];
    const int tid = threadIdx.x;
    const int b = blockIdx.x >> 5;
    const int q = ((blockIdx.x & 31) << 5) + (tid >> 3);
    const int l = tid & 7;
    const float* bp = P + (size_t)b * NT * NN * 3;

    float cx = bp[q * 3 + 0], cy = bp[q * 3 + 1], cz = bp[q * 3 + 2];

    for (int t = 0; t < NT; ++t) {
        // stage frame t with |p|^2 (thread i -> candidates 4i..4i+3)
        const float4* f4 = (const float4*)(bp + (size_t)t * NN * 3);
        float4 A = f4[tid * 3 + 0], Bv = f4[tid * 3 + 1], C = f4[tid * 3 + 2];
        sF[tid * 4 + 0] = make_float4(A.x, A.y, A.z, sq3(A.x, A.y, A.z));
        sF[tid * 4 + 1] = make_float4(A.w, Bv.x, Bv.y, sq3(A.w, Bv.x, Bv.y));
        sF[tid * 4 + 2] = make_float4(Bv.z, Bv.w, C.x, sq3(Bv.z, Bv.w, C.x));
        sF[tid * 4 + 3] = make_float4(C.y, C.z, C.w, sq3(C.y, C.z, C.w));
        __syncthreads();

        float q2 = sq3(cx, cy, cz);
        u64 best = ~0ull;
        #pragma unroll 8
        for (int jj = 0; jj < NN / 8; ++jj) {
            int j = (jj << 3) | l;  // interleaved -> conflict-free b128 broadcast
            float d2 = d2f(cx, cy, cz, q2, sF[j]);
            u64 key = ((u64)fmap(d2) << 32) | (u32)j;
            if (key < best) best = key;
        }
        // reduce argmin across the 8 lanes of this query's group
        #pragma unroll
        for (int off = 1; off < 8; off <<= 1) {
            u64 o = __shfl_xor(best, off);
            if (o < best) best = o;
        }
        int bi = (int)(u32)best;
        float4 w = sF[bi];
        cx = w.x; cy = w.y; cz = w.z;
        if (l == 0) {
            float* o = outx + ((size_t)(b * NT + t) * NN + q) * 3;
            o[0] = cx; o[1] = cy; o[2] = cz;
        }
        __syncthreads();
    }
}

// ---------------- Phase 2: full top-16 + all outputs, fully parallel over (b,t,q) ----
// grid: 1024 blocks (b:8 x t:32 x qchunk:4), block: 256 threads = 256 queries
// 32-bit selection state: K[16] sorted f32 d2 (min/max update, mask-free),
// ID[16] u32 indices (cndmask chain). Stability of the strict-< insert under
// ascending j reproduces top_k's lowest-index-first tie-break exactly.
__global__ __launch_bounds__(256, 4) void topk_k(const float* __restrict__ P,
                                                 const float* __restrict__ outx,
                                                 float* __restrict__ out) {
    __shared__ float4 sC[NN];  // frame t   (x,y,z,|p|^2)
    __shared__ float4 sPv[NN]; // frame t-1 (x,y,z,0)
    const int tid = threadIdx.x;
    const int bid = blockIdx.x;
    const int b = bid >> 7;
    const int t = (bid >> 2) & 31;
    const int qc = bid & 3;
    const int q = (qc << 8) | tid;
    const float* bp = P + (size_t)b * NT * NN * 3;

    {
        const float4* f4 = (const float4*)(bp + (size_t)t * NN * 3);
        float4 A = f4[tid * 3 + 0], Bv = f4[tid * 3 + 1], C = f4[tid * 3 + 2];
        sC[tid * 4 + 0] = make_float4(A.x, A.y, A.z, sq3(A.x, A.y, A.z));
        sC[tid * 4 + 1] = make_float4(A.w, Bv.x, Bv.y, sq3(A.w, Bv.x, Bv.y));
        sC[tid * 4 + 2] = make_float4(Bv.z, Bv.w, C.x, sq3(Bv.z, Bv.w, C.x));
        sC[tid * 4 + 3] = make_float4(C.y, C.z, C.w, sq3(C.y, C.z, C.w));
        int tp = (t == 0) ? 0 : (t - 1);
        const float4* g4 = (const float4*)(bp + (size_t)tp * NN * 3);
        A = g4[tid * 3 + 0]; Bv = g4[tid * 3 + 1]; C = g4[tid * 3 + 2];
        sPv[tid * 4 + 0] = make_float4(A.x, A.y, A.z, 0.f);
        sPv[tid * 4 + 1] = make_float4(A.w, Bv.x, Bv.y, 0.f);
        sPv[tid * 4 + 2] = make_float4(Bv.z, Bv.w, C.x, 0.f);
        sPv[tid * 4 + 3] = make_float4(C.y, C.z, C.w, 0.f);
    }
    __syncthreads();

    // query point: x_cur(b,t,q)
    float cx, cy, cz;
    if (t == 0) {
        const float* qp = bp + (size_t)q * 3;
        cx = qp[0]; cy = qp[1]; cz = qp[2];
    } else {
        const float* qp = outx + ((size_t)(b * NT + (t - 1)) * NN + q) * 3;
        cx = qp[0]; cy = qp[1]; cz = qp[2];
    }
    // anchor = pts[b, t=0, q, k=0] = outx[b][0][q]
    const float* ap = outx + ((size_t)(b * NT) * NN + q) * 3;
    float ax = ap[0], ay = ap[1], az = ap[2];

    float q2 = sq3(cx, cy, cz);
    float K[KSEL];
    u32 ID[KSEL];
    #pragma unroll
    for (int i = 0; i < KSEL; i++) { K[i] = __uint_as_float(0x7F800000u); ID[i] = 0u; }

    #pragma unroll 8
    for (int j = 0; j < NN; ++j) {
        float d2 = d2f(cx, cy, cz, q2, sC[j]);
        bool lt[KSEL];
        #pragma unroll
        for (int i = 0; i < KSEL; i++) lt[i] = d2 < K[i];
        // descending i: K[i-1]/ID[i-1] still hold old values
        #pragma unroll
        for (int i = KSEL - 1; i >= 1; --i) {
            K[i]  = fminf(fmaxf(d2, K[i - 1]), K[i]);
            ID[i] = lt[i - 1] ? ID[i - 1] : (lt[i] ? (u32)j : ID[i]);
        }
        K[0]  = fminf(d2, K[0]);
        ID[0] = lt[0] ? (u32)j : ID[0];
    }

    size_t g = (size_t)(b * NT + t) * NN + q;

    // idxs (x2) and dist
    #pragma unroll
    for (int kk = 0; kk < KSEL; kk += 4) {
        float4 fi = make_float4((float)ID[kk + 0], (float)ID[kk + 1],
                                (float)ID[kk + 2], (float)ID[kk + 3]);
        float4 fd = make_float4(K[kk + 0], K[kk + 1], K[kk + 2], K[kk + 3]);
        *(float4*)(out + O_IDX0 + g * 16 + kk) = fi;
        *(float4*)(out + O_IDX1 + g * 16 + kk) = fi;
        *(float4*)(out + O_DIST + g * 16 + kk) = fd;
    }

    // pts, normalized, patchlet_feats
    #pragma unroll
    for (int kk = 0; kk < KSEL; kk += 4) {
        u32 i0 = ID[kk + 0], i1 = ID[kk + 1], i2 = ID[kk + 2], i3 = ID[kk + 3];
        float4 p0 = sC[i0], p1 = sC[i1], p2v = sC[i2], p3 = sC[i3];
        float4 f0 = sPv[i0], f1 = sPv[i1], f2v = sPv[i2], f3 = sPv[i3];
        float n0x = p0.x - ax, n0y = p0.y - ay, n0z = p0.z - az;
        float n1x = p1.x - ax, n1y = p1.y - ay, n1z = p1.z - az;
        float n2x = p2v.x - ax, n2y = p2v.y - ay, n2z = p2v.z - az;
        float n3x = p3.x - ax, n3y = p3.y - ay, n3z = p3.z - az;

        float* pp = out + O_PTS + g * 48 + kk * 3;
        ((float4*)pp)[0] = make_float4(p0.x, p0.y, p0.z, p1.x);
        ((float4*)pp)[1] = make_float4(p1.y, p1.z, p2v.x, p2v.y);
        ((float4*)pp)[2] = make_float4(p2v.z, p3.x, p3.y, p3.z);

        float* np = out + O_NORM + g * 48 + kk * 3;
        ((float4*)np)[0] = make_float4(n0x, n0y, n0z, n1x);
        ((float4*)np)[1] = make_float4(n1y, n1z, n2x, n2y);
        ((float4*)np)[2] = make_float4(n2z, n3x, n3y, n3z);

        float* fp = out + O_PF + g * 96 + kk * 6;
        ((float4*)fp)[0] = make_float4(f0.x, f0.y, f0.z, n0x);
        ((float4*)fp)[1] = make_float4(n0y, n0z, f1.x, f1.y);
        ((float4*)fp)[2] = make_float4(f1.z, n1x, n1y, n1z);
        ((float4*)fp)[3] = make_float4(f2v.x, f2v.y, f2v.z, n2x);
        ((float4*)fp)[4] = make_float4(n2y, n2z, f3.x, f3.y);
        ((float4*)fp)[5] = make_float4(f3.z, n3x, n3y, n3z);
    }
}

extern "C" void kernel_launch(void* const* d_in, const int* in_sizes, int n_in,
                              void* d_out, int out_size, void* d_ws, size_t ws_size,
                              hipStream_t stream) {
    const float* P = (const float*)d_in[0];
    float* out = (float*)d_out;
    float* outx = out + O_OUTX;
    chain_k<<<dim3(256), dim3(256), 0, stream>>>(P, outx);
    topk_k<<<dim3(1024), dim3(256), 0, stream>>>(P, outx, out);
}

// Round 6
// 490.869 us; speedup vs baseline: 2.1513x; 1.6655x over previous
//
#include <hip/hip_runtime.h>
#include <stdint.h>

#define NB 8
#define NT 32
#define NN 1024
#define KSEL 16
#define CHUNK 64
#define NCHUNK (NN / CHUNK)

typedef unsigned long long u64;
typedef unsigned int u32;

// total output element offsets (all float32)
#define O_IDX0 0ull
#define O_DIST 4194304ull
#define O_IDX1 8388608ull
#define O_PTS  12582912ull
#define O_PF   25165824ull
#define O_NORM 50331648ull
#define O_OUTX 62914560ull

#define F32_INF __uint_as_float(0x7F800000u)

__device__ __forceinline__ u32 fmap(float f) {
    u32 b = __float_as_uint(f);
    u32 m = (u32)((int)b >> 31) | 0x80000000u;
    return b ^ m;
}
// XLA-CPU reduce(sum(x*x)) with LLVM FMA contraction:
// acc=add(acc,elem) chain -> fma(z,z, fma(x,x, y*y))
__device__ __forceinline__ float sq3(float x, float y, float z) {
    return __fmaf_rn(z, z, __fmaf_rn(x, x, __fmul_rn(y, y)));
}
// Eigen sgemm ascending-k FMA dot; d2 = (q2+p2) - 2*dot (2*dot exact)
__device__ __forceinline__ float d2f(float qx, float qy, float qz, float q2, float4 c) {
    float dot = __fmul_rn(qx, c.x);
    dot = __fmaf_rn(qy, c.y, dot);
    dot = __fmaf_rn(qz, c.z, dot);
    return __fsub_rn(__fadd_rn(q2, c.w), __fadd_rn(dot, dot));
}

// ---------------- Phase 1: nearest-neighbor chain (k=1), writes outx ----------------
// grid: 256 blocks (8 batches x 32), block: 256 threads = 32 queries x 8 lanes
__global__ __launch_bounds__(256) void chain_k(const float* __restrict__ P,
                                               float* __restrict__ outx) {
    __shared__ float4 sF[NN];
    const int tid = threadIdx.x;
    const int b = blockIdx.x >> 5;
    const int q = ((blockIdx.x & 31) << 5) + (tid >> 3);
    const int l = tid & 7;
    const float* bp = P + (size_t)b * NT * NN * 3;

    float cx = bp[q * 3 + 0], cy = bp[q * 3 + 1], cz = bp[q * 3 + 2];

    for (int t = 0; t < NT; ++t) {
        // stage frame t with |p|^2 (thread i -> candidates 4i..4i+3)
        const float4* f4 = (const float4*)(bp + (size_t)t * NN * 3);
        float4 A = f4[tid * 3 + 0], Bv = f4[tid * 3 + 1], C = f4[tid * 3 + 2];
        sF[tid * 4 + 0] = make_float4(A.x, A.y, A.z, sq3(A.x, A.y, A.z));
        sF[tid * 4 + 1] = make_float4(A.w, Bv.x, Bv.y, sq3(A.w, Bv.x, Bv.y));
        sF[tid * 4 + 2] = make_float4(Bv.z, Bv.w, C.x, sq3(Bv.z, Bv.w, C.x));
        sF[tid * 4 + 3] = make_float4(C.y, C.z, C.w, sq3(C.y, C.z, C.w));
        __syncthreads();

        float q2 = sq3(cx, cy, cz);
        u64 best = ~0ull;
        #pragma unroll 8
        for (int jj = 0; jj < NN / 8; ++jj) {
            int j = (jj << 3) | l;  // interleaved -> conflict-free b128 broadcast
            float d2 = d2f(cx, cy, cz, q2, sF[j]);
            u64 key = ((u64)fmap(d2) << 32) | (u32)j;
            if (key < best) best = key;
        }
        // reduce argmin across the 8 lanes of this query's group
        #pragma unroll
        for (int off = 1; off < 8; off <<= 1) {
            u64 o = __shfl_xor(best, off);
            if (o < best) best = o;
        }
        int bi = (int)(u32)best;
        float4 w = sF[bi];
        cx = w.x; cy = w.y; cz = w.z;
        if (l == 0) {
            float* o = outx + ((size_t)(b * NT + t) * NN + q) * 3;
            o[0] = cx; o[1] = cy; o[2] = cz;
        }
        __syncthreads();
    }
}

// ---------------- Phase 2: filter + buffered exact replay top-16 ----------------
// grid: 1024 blocks (b:8 x t:32 x qchunk:4), block: 256 threads = 256 queries.
// Hot loop only filters (d2 < stale-K15 threshold); survivors' j buffered in a
// per-lane LDS FIFO ([entry][tid] layout, conflict-free). Flush after each
// 64-candidate chunk replays survivors through the exact stable insert
// (med3 K-update + cndmask ID chain). Stale threshold >= running K15 =>
// survivor set is a superset of state-changing candidates => replay is
// bitwise-identical to the full stream (ties included).
__global__ __launch_bounds__(256) void topk_k(const float* __restrict__ P,
                                              const float* __restrict__ outx,
                                              float* __restrict__ out) {
    __shared__ float4 sC[NN];                 // frame t   (x,y,z,|p|^2) 16KB
    __shared__ float4 sPv[NN];                // frame t-1 (x,y,z,0)     16KB
    __shared__ unsigned short sBuf[CHUNK * 256]; // per-lane FIFO        32KB
    const int tid = threadIdx.x;
    const int bid = blockIdx.x;
    const int b = bid >> 7;
    const int t = (bid >> 2) & 31;
    const int qc = bid & 3;
    const int q = (qc << 8) | tid;
    const float* bp = P + (size_t)b * NT * NN * 3;

    {
        const float4* f4 = (const float4*)(bp + (size_t)t * NN * 3);
        float4 A = f4[tid * 3 + 0], Bv = f4[tid * 3 + 1], C = f4[tid * 3 + 2];
        sC[tid * 4 + 0] = make_float4(A.x, A.y, A.z, sq3(A.x, A.y, A.z));
        sC[tid * 4 + 1] = make_float4(A.w, Bv.x, Bv.y, sq3(A.w, Bv.x, Bv.y));
        sC[tid * 4 + 2] = make_float4(Bv.z, Bv.w, C.x, sq3(Bv.z, Bv.w, C.x));
        sC[tid * 4 + 3] = make_float4(C.y, C.z, C.w, sq3(C.y, C.z, C.w));
        int tp = (t == 0) ? 0 : (t - 1);
        const float4* g4 = (const float4*)(bp + (size_t)tp * NN * 3);
        A = g4[tid * 3 + 0]; Bv = g4[tid * 3 + 1]; C = g4[tid * 3 + 2];
        sPv[tid * 4 + 0] = make_float4(A.x, A.y, A.z, 0.f);
        sPv[tid * 4 + 1] = make_float4(A.w, Bv.x, Bv.y, 0.f);
        sPv[tid * 4 + 2] = make_float4(Bv.z, Bv.w, C.x, 0.f);
        sPv[tid * 4 + 3] = make_float4(C.y, C.z, C.w, 0.f);
    }
    __syncthreads();

    // query point: x_cur(b,t,q)
    float cx, cy, cz;
    if (t == 0) {
        const float* qp = bp + (size_t)q * 3;
        cx = qp[0]; cy = qp[1]; cz = qp[2];
    } else {
        const float* qp = outx + ((size_t)(b * NT + (t - 1)) * NN + q) * 3;
        cx = qp[0]; cy = qp[1]; cz = qp[2];
    }
    // anchor = pts[b, t=0, q, k=0] = outx[b][0][q]
    const float* ap = outx + ((size_t)(b * NT) * NN + q) * 3;
    float ax = ap[0], ay = ap[1], az = ap[2];

    float q2 = sq3(cx, cy, cz);
    float K[KSEL];
    u32 ID[KSEL];
    #pragma unroll
    for (int i = 0; i < KSEL; i++) { K[i] = F32_INF; ID[i] = 0u; }
    float thr = F32_INF;

    for (int ch = 0; ch < NCHUNK; ++ch) {
        int cnt = 0;
        // ---- filter pass over this chunk (cheap) ----
        #pragma unroll 8
        for (int jj = 0; jj < CHUNK; ++jj) {
            int j = (ch << 6) | jj;
            float d2 = d2f(cx, cy, cz, q2, sC[j]);
            bool hit = d2 < thr;
            sBuf[cnt * 256 + tid] = (unsigned short)j;  // unconditional; garbage overwritten
            cnt += hit ? 1 : 0;
        }
        // ---- wave-max of cnt -> uniform flush trip count ----
        int cm = cnt;
        #pragma unroll
        for (int off = 1; off < 64; off <<= 1) {
            int o = __shfl_xor(cm, off);
            cm = (o > cm) ? o : cm;
        }
        cm = __builtin_amdgcn_readfirstlane(cm);
        // ---- exact stable-insert replay of survivors (ascending j) ----
        for (int i = 0; i < cm; ++i) {
            u32 jj = sBuf[i * 256 + tid];
            float4 c = sC[jj];
            float d2 = d2f(cx, cy, cz, q2, c);
            d2 = (i < cnt) ? d2 : F32_INF;  // neutralize lanes past their count
            bool lt[KSEL];
            #pragma unroll
            for (int s = 0; s < KSEL; s++) lt[s] = d2 < K[s];
            #pragma unroll
            for (int s = KSEL - 1; s >= 1; --s) {
                K[s]  = __builtin_fminf(__builtin_fmaxf(d2, K[s - 1]), K[s]); // == med3
                ID[s] = lt[s - 1] ? ID[s - 1] : (lt[s] ? jj : ID[s]);
            }
            K[0]  = __builtin_fminf(d2, K[0]);
            ID[0] = lt[0] ? jj : ID[0];
        }
        thr = K[KSEL - 1];
    }

    size_t g = (size_t)(b * NT + t) * NN + q;

    // idxs (x2) and dist
    #pragma unroll
    for (int kk = 0; kk < KSEL; kk += 4) {
        float4 fi = make_float4((float)ID[kk + 0], (float)ID[kk + 1],
                                (float)ID[kk + 2], (float)ID[kk + 3]);
        float4 fd = make_float4(K[kk + 0], K[kk + 1], K[kk + 2], K[kk + 3]);
        *(float4*)(out + O_IDX0 + g * 16 + kk) = fi;
        *(float4*)(out + O_IDX1 + g * 16 + kk) = fi;
        *(float4*)(out + O_DIST + g * 16 + kk) = fd;
    }

    // pts, normalized, patchlet_feats
    #pragma unroll
    for (int kk = 0; kk < KSEL; kk += 4) {
        u32 i0 = ID[kk + 0], i1 = ID[kk + 1], i2 = ID[kk + 2], i3 = ID[kk + 3];
        float4 p0 = sC[i0], p1 = sC[i1], p2v = sC[i2], p3 = sC[i3];
        float4 f0 = sPv[i0], f1 = sPv[i1], f2v = sPv[i2], f3 = sPv[i3];
        float n0x = p0.x - ax, n0y = p0.y - ay, n0z = p0.z - az;
        float n1x = p1.x - ax, n1y = p1.y - ay, n1z = p1.z - az;
        float n2x = p2v.x - ax, n2y = p2v.y - ay, n2z = p2v.z - az;
        float n3x = p3.x - ax, n3y = p3.y - ay, n3z = p3.z - az;

        float* pp = out + O_PTS + g * 48 + kk * 3;
        ((float4*)pp)[0] = make_float4(p0.x, p0.y, p0.z, p1.x);
        ((float4*)pp)[1] = make_float4(p1.y, p1.z, p2v.x, p2v.y);
        ((float4*)pp)[2] = make_float4(p2v.z, p3.x, p3.y, p3.z);

        float* np = out + O_NORM + g * 48 + kk * 3;
        ((float4*)np)[0] = make_float4(n0x, n0y, n0z, n1x);
        ((float4*)np)[1] = make_float4(n1y, n1z, n2x, n2y);
        ((float4*)np)[2] = make_float4(n2z, n3x, n3y, n3z);

        float* fp = out + O_PF + g * 96 + kk * 6;
        ((float4*)fp)[0] = make_float4(f0.x, f0.y, f0.z, n0x);
        ((float4*)fp)[1] = make_float4(n0y, n0z, f1.x, f1.y);
        ((float4*)fp)[2] = make_float4(f1.z, n1x, n1y, n1z);
        ((float4*)fp)[3] = make_float4(f2v.x, f2v.y, f2v.z, n2x);
        ((float4*)fp)[4] = make_float4(n2y, n2z, f3.x, f3.y);
        ((float4*)fp)[5] = make_float4(f3.z, n3x, n3y, n3z);
    }
}

extern "C" void kernel_launch(void* const* d_in, const int* in_sizes, int n_in,
                              void* d_out, int out_size, void* d_ws, size_t ws_size,
                              hipStream_t stream) {
    const float* P = (const float*)d_in[0];
    float* out = (float*)d_out;
    float* outx = out + O_OUTX;
    chain_k<<<dim3(256), dim3(256), 0, stream>>>(P, outx);
    topk_k<<<dim3(1024), dim3(256), 0, stream>>>(P, outx, out);
}

// Round 9
// 425.019 us; speedup vs baseline: 2.4847x; 1.1549x over previous
//
#include <hip/hip_runtime.h>
#include <stdint.h>

#define NB 8
#define NT 32
#define NN 1024
#define KSEL 16

typedef unsigned long long u64;
typedef unsigned int u32;

// total output element offsets (all float32)
#define O_IDX0 0ull
#define O_DIST 4194304ull
#define O_IDX1 8388608ull
#define O_PTS  12582912ull
#define O_PF   25165824ull
#define O_NORM 50331648ull
#define O_OUTX 62914560ull

#define F32_INF __uint_as_float(0x7F800000u)

__device__ __forceinline__ u32 fmap(float f) {
    u32 b = __float_as_uint(f);
    u32 m = (u32)((int)b >> 31) | 0x80000000u;
    return b ^ m;
}
// XLA-CPU reduce(sum(x*x)) with LLVM FMA contraction: fma(z,z, fma(x,x, y*y))
__device__ __forceinline__ float sq3(float x, float y, float z) {
    return __fmaf_rn(z, z, __fmaf_rn(x, x, __fmul_rn(y, y)));
}
// Eigen sgemm ascending-k FMA dot; d2 = (q2+p2) - 2*dot (2*dot exact)
__device__ __forceinline__ float d2f(float qx, float qy, float qz, float q2, float4 c) {
    float dot = __fmul_rn(qx, c.x);
    dot = __fmaf_rn(qy, c.y, dot);
    dot = __fmaf_rn(qz, c.z, dot);
    return __fsub_rn(__fadd_rn(q2, c.w), __fadd_rn(dot, dot));
}

// ---------------- Phase 1: nearest-neighbor chain (k=1), writes outx ----------------
// r6-passing version, unchanged.
// grid: 256 blocks (8 batches x 32), block: 256 threads = 32 queries x 8 lanes
__global__ __launch_bounds__(256) void chain_k(const float* __restrict__ P,
                                               float* __restrict__ outx) {
    __shared__ float4 sF[NN];
    const int tid = threadIdx.x;
    const int b = blockIdx.x >> 5;
    const int q = ((blockIdx.x & 31) << 5) + (tid >> 3);
    const int l = tid & 7;
    const float* bp = P + (size_t)b * NT * NN * 3;

    float cx = bp[q * 3 + 0], cy = bp[q * 3 + 1], cz = bp[q * 3 + 2];

    for (int t = 0; t < NT; ++t) {
        // stage frame t with |p|^2 (thread i -> candidates 4i..4i+3)
        const float4* f4 = (const float4*)(bp + (size_t)t * NN * 3);
        float4 A = f4[tid * 3 + 0], Bv = f4[tid * 3 + 1], C = f4[tid * 3 + 2];
        sF[tid * 4 + 0] = make_float4(A.x, A.y, A.z, sq3(A.x, A.y, A.z));
        sF[tid * 4 + 1] = make_float4(A.w, Bv.x, Bv.y, sq3(A.w, Bv.x, Bv.y));
        sF[tid * 4 + 2] = make_float4(Bv.z, Bv.w, C.x, sq3(Bv.z, Bv.w, C.x));
        sF[tid * 4 + 3] = make_float4(C.y, C.z, C.w, sq3(C.y, C.z, C.w));
        __syncthreads();

        float q2 = sq3(cx, cy, cz);
        u64 best = ~0ull;
        #pragma unroll 8
        for (int jj = 0; jj < NN / 8; ++jj) {
            int j = (jj << 3) | l;  // interleaved -> conflict-free b128 broadcast
            float d2 = d2f(cx, cy, cz, q2, sF[j]);
            u64 key = ((u64)fmap(d2) << 32) | (u32)j;
            if (key < best) best = key;
        }
        // reduce argmin across the 8 lanes of this query's group
        #pragma unroll
        for (int off = 1; off < 8; off <<= 1) {
            u64 o = __shfl_xor(best, off);
            if (o < best) best = o;
        }
        int bi = (int)(u32)best;
        float4 w = sF[bi];
        cx = w.x; cy = w.y; cz = w.z;
        if (l == 0) {
            float* o = outx + ((size_t)(b * NT + t) * NN + q) * 3;
            o[0] = cx; o[1] = cy; o[2] = cz;
        }
        __syncthreads();
    }
}

// ---------------- Phase 2: exact LDS filter + bitmask replay top-16 ----------------
// BISECT r9: identical to r8 EXCEPT the insert uses r6's verified med3+lt[] form
// (swap-chain removed). If this passes, the swap-chain was the bug; if it fails
// at the same absmax, the bitmask walk is the bug.
__global__ __launch_bounds__(256, 4) void topk_k(const float* __restrict__ P,
                                                 const float* __restrict__ outx,
                                                 float* __restrict__ out) {
    __shared__ float4 sC[NN];  // frame t   (x,y,z,|p|^2) 16KB
    __shared__ float4 sPv[NN]; // frame t-1 (x,y,z,0)     16KB
    const int tid = threadIdx.x;
    const int bid = blockIdx.x;
    const int b = bid >> 7;
    const int t = (bid >> 2) & 31;
    const int qc = bid & 3;
    const int q = (qc << 8) | tid;
    const float* bp = P + (size_t)b * NT * NN * 3;

    {
        const float4* f4 = (const float4*)(bp + (size_t)t * NN * 3);
        float4 A = f4[tid * 3 + 0], Bv = f4[tid * 3 + 1], C = f4[tid * 3 + 2];
        sC[tid * 4 + 0] = make_float4(A.x, A.y, A.z, sq3(A.x, A.y, A.z));
        sC[tid * 4 + 1] = make_float4(A.w, Bv.x, Bv.y, sq3(A.w, Bv.x, Bv.y));
        sC[tid * 4 + 2] = make_float4(Bv.z, Bv.w, C.x, sq3(Bv.z, Bv.w, C.x));
        sC[tid * 4 + 3] = make_float4(C.y, C.z, C.w, sq3(C.y, C.z, C.w));
        int tp = (t == 0) ? 0 : (t - 1);
        const float4* g4 = (const float4*)(bp + (size_t)tp * NN * 3);
        A = g4[tid * 3 + 0]; Bv = g4[tid * 3 + 1]; C = g4[tid * 3 + 2];
        sPv[tid * 4 + 0] = make_float4(A.x, A.y, A.z, 0.f);
        sPv[tid * 4 + 1] = make_float4(A.w, Bv.x, Bv.y, 0.f);
        sPv[tid * 4 + 2] = make_float4(Bv.z, Bv.w, C.x, 0.f);
        sPv[tid * 4 + 3] = make_float4(C.y, C.z, C.w, 0.f);
    }
    __syncthreads();

    // query point: x_cur(b,t,q)
    float cx, cy, cz;
    if (t == 0) {
        const float* qp = bp + (size_t)q * 3;
        cx = qp[0]; cy = qp[1]; cz = qp[2];
    } else {
        const float* qp = outx + ((size_t)(b * NT + (t - 1)) * NN + q) * 3;
        cx = qp[0]; cy = qp[1]; cz = qp[2];
    }
    // anchor = pts[b, t=0, q, k=0] = outx[b][0][q]
    const float* ap = outx + ((size_t)(b * NT) * NN + q) * 3;
    float ax = ap[0], ay = ap[1], az = ap[2];

    float q2 = sq3(cx, cy, cz);
    float K[KSEL];
    u32 ID[KSEL];
    #pragma unroll
    for (int i = 0; i < KSEL; i++) { K[i] = F32_INF; ID[i] = 0u; }
    float thr = F32_INF;

    for (int ch = 0; ch < 16; ++ch) {
        // ---- exact filter: 64 candidates from LDS, survivor bits in 2 u32 ----
        u32 mlo = 0u, mhi = 0u;
        #pragma unroll
        for (int jj = 0; jj < 64; ++jj) {
            float d2 = d2f(cx, cy, cz, q2, sC[(ch << 6) | jj]);
            bool h = d2 < thr;
            if (jj < 32) mlo |= h ? (1u << jj) : 0u;
            else         mhi |= h ? (1u << (jj - 32)) : 0u;
        }
        u64 msk = ((u64)mhi << 32) | (u64)mlo;
        // ---- wave-max survivor count -> uniform counted replay ----
        int cnt = __builtin_popcountll(msk);
        int cm = cnt;
        #pragma unroll
        for (int off = 1; off < 64; off <<= 1) {
            int o = __shfl_xor(cm, off);
            cm = (o > cm) ? o : cm;
        }
        cm = __builtin_amdgcn_readfirstlane(cm);
        // ---- exact stable replay of survivors (ascending j), r6-verified insert ----
        for (int i = 0; i < cm; ++i) {
            bool act = msk != 0ull;
            u64 mm = act ? msk : 1ull;
            u32 jj = (u32)__builtin_ctzll(mm);
            msk &= (msk - 1ull);
            u32 j = (u32)(ch << 6) | jj;
            float4 c = sC[j];
            float d2 = d2f(cx, cy, cz, q2, c);
            float d2v = act ? d2 : F32_INF;  // neutralize exhausted lanes
            bool lt[KSEL];
            #pragma unroll
            for (int s = 0; s < KSEL; s++) lt[s] = d2v < K[s];
            #pragma unroll
            for (int s = KSEL - 1; s >= 1; --s) {
                K[s]  = __builtin_fminf(__builtin_fmaxf(d2v, K[s - 1]), K[s]); // == med3
                ID[s] = lt[s - 1] ? ID[s - 1] : (lt[s] ? j : ID[s]);
            }
            K[0]  = __builtin_fminf(d2v, K[0]);
            ID[0] = lt[0] ? j : ID[0];
        }
        thr = K[KSEL - 1];
    }

    size_t g = (size_t)(b * NT + t) * NN + q;

    // idxs (x2) and dist
    #pragma unroll
    for (int kk = 0; kk < KSEL; kk += 4) {
        float4 fi = make_float4((float)ID[kk + 0], (float)ID[kk + 1],
                                (float)ID[kk + 2], (float)ID[kk + 3]);
        float4 fd = make_float4(K[kk + 0], K[kk + 1], K[kk + 2], K[kk + 3]);
        *(float4*)(out + O_IDX0 + g * 16 + kk) = fi;
        *(float4*)(out + O_IDX1 + g * 16 + kk) = fi;
        *(float4*)(out + O_DIST + g * 16 + kk) = fd;
    }

    // pts, normalized, patchlet_feats
    #pragma unroll
    for (int kk = 0; kk < KSEL; kk += 4) {
        u32 i0 = ID[kk + 0], i1 = ID[kk + 1], i2 = ID[kk + 2], i3 = ID[kk + 3];
        float4 p0 = sC[i0], p1 = sC[i1], p2v = sC[i2], p3 = sC[i3];
        float4 f0 = sPv[i0], f1 = sPv[i1], f2v = sPv[i2], f3 = sPv[i3];
        float n0x = p0.x - ax, n0y = p0.y - ay, n0z = p0.z - az;
        float n1x = p1.x - ax, n1y = p1.y - ay, n1z = p1.z - az;
        float n2x = p2v.x - ax, n2y = p2v.y - ay, n2z = p2v.z - az;
        float n3x = p3.x - ax, n3y = p3.y - ay, n3z = p3.z - az;

        float* pp = out + O_PTS + g * 48 + kk * 3;
        ((float4*)pp)[0] = make_float4(p0.x, p0.y, p0.z, p1.x);
        ((float4*)pp)[1] = make_float4(p1.y, p1.z, p2v.x, p2v.y);
        ((float4*)pp)[2] = make_float4(p2v.z, p3.x, p3.y, p3.z);

        float* np = out + O_NORM + g * 48 + kk * 3;
        ((float4*)np)[0] = make_float4(n0x, n0y, n0z, n1x);
        ((float4*)np)[1] = make_float4(n1y, n1z, n2x, n2y);
        ((float4*)np)[2] = make_float4(n2z, n3x, n3y, n3z);

        float* fp = out + O_PF + g * 96 + kk * 6;
        ((float4*)fp)[0] = make_float4(f0.x, f0.y, f0.z, n0x);
        ((float4*)fp)[1] = make_float4(n0y, n0z, f1.x, f1.y);
        ((float4*)fp)[2] = make_float4(f1.z, n1x, n1y, n1z);
        ((float4*)fp)[3] = make_float4(f2v.x, f2v.y, f2v.z, n2x);
        ((float4*)fp)[4] = make_float4(n2y, n2z, f3.x, f3.y);
        ((float4*)fp)[5] = make_float4(f3.z, n3x, n3y, n3z);
    }
}

extern "C" void kernel_launch(void* const* d_in, const int* in_sizes, int n_in,
                              void* d_out, int out_size, void* d_ws, size_t ws_size,
                              hipStream_t stream) {
    const float* P = (const float*)d_in[0];
    float* out = (float*)d_out;
    float* outx = out + O_OUTX;
    chain_k<<<dim3(256), dim3(256), 0, stream>>>(P, outx);
    topk_k<<<dim3(1024), dim3(256), 0, stream>>>(P, outx, out);
}